// Round 3
// baseline (261.347 us; speedup 1.0000x reference)
//
#include <hip/hip_runtime.h>
#include <cstdint>
#include <cstddef>

typedef __bf16 bf16x8 __attribute__((ext_vector_type(8)));
typedef float  f32x4  __attribute__((ext_vector_type(4)));

static __device__ __forceinline__ unsigned short f2bf(float f) {
    union { float f; unsigned int u; } v;
    v.f = f;
    unsigned int r = v.u + 0x7FFFu + ((v.u >> 16) & 1u);
    return (unsigned short)(r >> 16);
}

static __device__ __forceinline__ float sigm(float x) {
    return 1.0f / (1.0f + __expf(-x));
}
static __device__ __forceinline__ float tanh_f(float x) {
    float e = __expf(2.0f * x);
    return 1.0f - 2.0f / (e + 1.0f);
}

#define GLD16(srcp, dstp) __builtin_amdgcn_global_load_lds( \
    (__attribute__((address_space(1))) void*)(srcp),        \
    (__attribute__((address_space(3))) void*)(dstp), 16, 0, 0)

// ---------------- prep kernels ----------------

__global__ void embed_cat(const int* __restrict__ bv, const int* __restrict__ i0,
                          const int* __restrict__ i1, const int* __restrict__ i2,
                          const int* __restrict__ i3, const float* __restrict__ num,
                          const float* __restrict__ bt, const float* __restrict__ t0,
                          const float* __restrict__ t1, const float* __restrict__ t2,
                          const float* __restrict__ t3, unsigned short* __restrict__ XB0)
{
    int col = blockIdx.x * 256 + threadIdx.x;
    int row = blockIdx.y;
    if (col >= 1472) return;
    int t = col / 92;
    int c = col - t * 92;
    int p = row * 16 + t;
    float v;
    if (c < 32)      v = bt[bv[p] * 32 + c];
    else if (c < 45) v = t0[i0[p] * 13 + (c - 32)];
    else if (c < 51) v = t1[i1[p] * 6  + (c - 45)];
    else if (c < 55) v = t2[i2[p] * 4  + (c - 51)];
    else if (c < 84) v = t3[i3[p] * 29 + (c - 55)];
    else             v = num[p * 8 + (c - 84)];
    XB0[(size_t)row * 1984 + col] = f2bf(v);
}

__global__ void h0_cast(const float* __restrict__ h0, unsigned short* __restrict__ XB0,
                        unsigned short* __restrict__ XB1)
{
    int col = blockIdx.x * 256 + threadIdx.x;   // 0..511
    int row = blockIdx.y;
    XB0[(size_t)row * 1984 + 1472 + col] = f2bf(h0[(size_t)row * 512 + col]);
    XB1[(size_t)row * 1024 + 512  + col] = f2bf(h0[(size_t)4194304 + (size_t)row * 512 + col]);
}

__global__ void pack_w(const float* __restrict__ Wih, const float* __restrict__ Whh,
                       unsigned short* __restrict__ WB, int Kih, int Ktot)
{
    int col = blockIdx.x * 256 + threadIdx.x;
    int np  = blockIdx.y;
    if (col >= Ktot) return;
    int jj = np >> 2, g = np & 3;
    int src = g * 512 + jj;
    float v = (col < Kih) ? Wih[(size_t)src * Kih + col]
                          : Whh[(size_t)src * 512 + (col - Kih)];
    WB[(size_t)np * Ktot + col] = f2bf(v);
}

__global__ void cast_w(const float* __restrict__ W, unsigned short* __restrict__ WB, int n) {
    int i = blockIdx.x * 256 + threadIdx.x;
    if (i < n) WB[i] = f2bf(W[i]);
}

__global__ void pack_bias(const float* __restrict__ bi0, const float* __restrict__ bh0,
                          const float* __restrict__ bi1, const float* __restrict__ bh1,
                          float* __restrict__ B0, float* __restrict__ B1)
{
    int np = blockIdx.x * 256 + threadIdx.x;   // 0..2047
    int jj = np >> 2, g = np & 3;
    int src = g * 512 + jj;
    B0[np] = bi0[src] + bh0[src];
    B1[np] = bi1[src] + bh1[src];
}

// ---------------- fused GEMM (+optional LSTM epilogue) ----------------
// C[m][n'] = sum_k A[m][k] * Bw[n'][k]   (A: [M][K] bf16, Bw: [N][K] bf16, both row-major)
// Tile 128x128, BK=64, 4 waves (2x2), each wave 64x64 via 4x4 mfma_f32_16x16x32_bf16 frags.
// launch_bounds(256,3): 3 blocks/CU (LDS 51.2KB*3 <= 160KB; regs 72V+64A=136 <= 170).
// Round-2 post-mortem: (256,2) capped occupancy at 22.5% -> MfmaUtil 21.6%.
template<int K, bool LSTM, int NOUT>
__global__ __launch_bounds__(256, 3)
void gemm_fused(const unsigned short* __restrict__ A,
                const unsigned short* __restrict__ Bw,
                const float* __restrict__ bias,      // LSTM: interleaved b_ih+b_hh [2048]; else b_out
                const float* __restrict__ c_in,      // LSTM: [M][512]
                float* __restrict__ h_out,           // LSTM: [M][512]
                float* __restrict__ c_out,           // LSTM: [M][512]
                unsigned short* __restrict__ h_bf,   // LSTM: bf16 h for next GEMM
                int hb_stride,
                float* __restrict__ out_plain)       // !LSTM: [M][NOUT]
{
    __shared__ __align__(16) unsigned short As[128 * 64];
    __shared__ __align__(16) unsigned short Bs[128 * 64];
    __shared__ __align__(16) float gt[4][16 * 72];

    const int tid  = threadIdx.x;
    const int lane = tid & 63;
    const int wid  = tid >> 6;
    const int wm   = wid >> 1;
    const int wn   = wid & 1;
    const int rowBase = blockIdx.y * 128;
    const int colBase = blockIdx.x * 128;

    const int lr = lane >> 3;          // row within 8-row chunk
    const int lc = (lane & 7) * 8;     // col (elements) within 64

    f32x4 acc[4][4] = {};

    const unsigned short* aSrc0 = A  + (size_t)(rowBase + wid * 32 + lr) * K + lc;
    const unsigned short* bSrc0 = Bw + (size_t)(colBase + wid * 32 + lr) * K + lc;

    #pragma unroll 1
    for (int k0 = 0; k0 < K; k0 += 64) {
        #pragma unroll
        for (int t = 0; t < 4; ++t)
            GLD16(aSrc0 + (size_t)t * 8 * K + k0, &As[(wid * 4 + t) * 512]);
        #pragma unroll
        for (int t = 0; t < 4; ++t)
            GLD16(bSrc0 + (size_t)t * 8 * K + k0, &Bs[(wid * 4 + t) * 512]);
        __syncthreads();
        #pragma unroll
        for (int ks = 0; ks < 2; ++ks) {
            bf16x8 af[4], bfr[4];
            #pragma unroll
            for (int i = 0; i < 4; ++i)
                af[i] = *(const bf16x8*)&As[(wm * 64 + i * 16 + (lane & 15)) * 64 + ks * 32 + (lane >> 4) * 8];
            #pragma unroll
            for (int i = 0; i < 4; ++i)
                bfr[i] = *(const bf16x8*)&Bs[(wn * 64 + i * 16 + (lane & 15)) * 64 + ks * 32 + (lane >> 4) * 8];
            #pragma unroll
            for (int i = 0; i < 4; ++i) {
                #pragma unroll
                for (int j = 0; j < 4; ++j)
                    acc[i][j] = __builtin_amdgcn_mfma_f32_16x16x32_bf16(af[i], bfr[j], acc[i][j], 0, 0, 0);
            }
        }
        __syncthreads();
    }

    if constexpr (!LSTM) {
        // plain epilogue: out = acc + bias (C layout: col=lane&15, row=(lane>>4)*4+r, m89-verified)
        #pragma unroll
        for (int i = 0; i < 4; ++i) {
            int grow = rowBase + wm * 64 + i * 16 + (lane >> 4) * 4;
            #pragma unroll
            for (int j = 0; j < 4; ++j) {
                int gcol = colBase + wn * 64 + j * 16 + (lane & 15);
                float b = bias[gcol];
                #pragma unroll
                for (int r = 0; r < 4; ++r)
                    out_plain[(size_t)(grow + r) * NOUT + gcol] = acc[i][j][r] + b;
            }
        }
    } else {
        // LSTM epilogue: cols are interleaved gates n' = 4*j + {i,f,g,o}
        // NOTE: i-loop MUST be fully unrolled — a rolled loop makes acc[i][..]
        // runtime-indexed and demotes the whole accumulator to scratch
        // (rule #20; round-1 post-mortem: 3 GB scratch writebacks, MfmaUtil 0.6%).
        float* gtw = gt[wid];
        const int jBase = (colBase + wn * 64) >> 2;   // global hidden-unit base (16 per wave tile)
        #pragma unroll
        for (int i = 0; i < 4; ++i) {
            #pragma unroll
            for (int j = 0; j < 4; ++j) {
                int cl = j * 16 + (lane & 15);
                int rl = (lane >> 4) * 4;
                #pragma unroll
                for (int r = 0; r < 4; ++r)
                    gtw[(rl + r) * 72 + cl] = acc[i][j][r];
            }
            __syncthreads();
            #pragma unroll
            for (int q = 0; q < 4; ++q) {
                int p  = lane + q * 64;            // 256 outputs: 16 rows x 16 hidden units
                int rl = p >> 4;
                int jl = p & 15;
                float4 g4 = *(const float4*)&gtw[rl * 72 + jl * 4];
                float4 b4 = *(const float4*)&bias[(jBase + jl) * 4];
                float xi = g4.x + b4.x;
                float xf = g4.y + b4.y;
                float xg = g4.z + b4.z;
                float xo = g4.w + b4.w;
                float iv = sigm(xi), fv = sigm(xf), gv = tanh_f(xg), ov = sigm(xo);
                int grow = rowBase + wm * 64 + i * 16 + rl;
                int gj   = jBase + jl;
                size_t idx = (size_t)grow * 512 + gj;
                float cp = c_in[idx];
                float cn = fv * cp + iv * gv;
                float hn = ov * tanh_f(cn);
                h_out[idx] = hn;
                c_out[idx] = cn;
                h_bf[(size_t)grow * hb_stride + gj] = f2bf(hn);
            }
            __syncthreads();
        }
    }
}

// ---------------- launch ----------------

extern "C" void kernel_launch(void* const* d_in, const int* in_sizes, int n_in,
                              void* d_out, int out_size, void* d_ws, size_t ws_size,
                              hipStream_t stream) {
    (void)in_sizes; (void)n_in; (void)out_size; (void)ws_size;

    const int*   byte_vals = (const int*)d_in[0];
    const int*   ci0       = (const int*)d_in[1];
    const int*   ci1       = (const int*)d_in[2];
    const int*   ci2       = (const int*)d_in[3];
    const int*   ci3       = (const int*)d_in[4];
    const float* numer     = (const float*)d_in[5];
    const float* h0        = (const float*)d_in[6];
    const float* c0        = (const float*)d_in[7];
    const float* byte_tab  = (const float*)d_in[8];
    const float* cat_t0    = (const float*)d_in[9];
    const float* cat_t1    = (const float*)d_in[10];
    const float* cat_t2    = (const float*)d_in[11];
    const float* cat_t3    = (const float*)d_in[12];
    const float* W_ih0     = (const float*)d_in[13];
    const float* W_hh0     = (const float*)d_in[14];
    const float* b_ih0     = (const float*)d_in[15];
    const float* b_hh0     = (const float*)d_in[16];
    const float* W_ih1     = (const float*)d_in[17];
    const float* W_hh1     = (const float*)d_in[18];
    const float* b_ih1     = (const float*)d_in[19];
    const float* b_hh1     = (const float*)d_in[20];
    const float* W_out     = (const float*)d_in[21];
    const float* b_out     = (const float*)d_in[22];

    char* ws = (char*)d_ws;
    unsigned short* XB0 = (unsigned short*)(ws);               // 8192*1984*2 = 32,505,856
    unsigned short* XB1 = (unsigned short*)(ws + 32505856);    // 8192*1024*2 = 16,777,216
    unsigned short* WB0 = (unsigned short*)(ws + 49283072);    // 2048*1984*2 =  8,126,464
    unsigned short* WB1 = (unsigned short*)(ws + 57409536);    // 2048*1024*2 =  4,194,304
    unsigned short* WoB = (unsigned short*)(ws + 61603840);    // 256*512*2   =    262,144
    float*          B0  = (float*)(ws + 61865984);             // 2048*4
    float*          B1  = (float*)(ws + 61874176);             // 2048*4  (end 61,882,368)
    unsigned short* H2B = XB0;                                 // alias: XB0 dead after GEMM0

    float* out    = (float*)d_out;
    float* logits = out;                        // [8192][256]
    float* h1o    = out + 2097152;              // h stack [0]
    float* h2o    = out + 2097152 + 4194304;    // h stack [1]
    float* c1o    = out + 2097152 + 8388608;    // c stack [0]
    float* c2o    = out + 2097152 + 12582912;   // c stack [1]
    const float* c0_0 = c0;
    const float* c0_1 = c0 + 4194304;

    // prep
    embed_cat<<<dim3(6, 8192), 256, 0, stream>>>(byte_vals, ci0, ci1, ci2, ci3, numer,
                                                 byte_tab, cat_t0, cat_t1, cat_t2, cat_t3, XB0);
    h0_cast<<<dim3(2, 8192), 256, 0, stream>>>(h0, XB0, XB1);
    pack_w<<<dim3(8, 2048), 256, 0, stream>>>(W_ih0, W_hh0, WB0, 1472, 1984);
    pack_w<<<dim3(4, 2048), 256, 0, stream>>>(W_ih1, W_hh1, WB1, 512, 1024);
    cast_w<<<dim3(512), 256, 0, stream>>>(W_out, WoB, 131072);
    pack_bias<<<dim3(8), 256, 0, stream>>>(b_ih0, b_hh0, b_ih1, b_hh1, B0, B1);

    // layer 0: gates0 = [x | h0_0] @ [W_ih0 | W_hh0]^T (interleaved), fused LSTM -> h1,c1, h1_bf16 -> XB1[:, :512]
    gemm_fused<1984, true, 512><<<dim3(16, 64), 256, 0, stream>>>(
        XB0, WB0, B0, c0_0, h1o, c1o, XB1, 1024, nullptr);

    // layer 1: gates1 = [h1 | h0_1] @ [W_ih1 | W_hh1]^T, fused LSTM -> h2,c2, h2_bf16 -> H2B
    gemm_fused<1024, true, 512><<<dim3(16, 64), 256, 0, stream>>>(
        XB1, WB1, B1, c0_1, h2o, c2o, H2B, 512, nullptr);

    // logits = h2 @ W_out^T + b_out
    gemm_fused<512, false, 256><<<dim3(2, 64), 256, 0, stream>>>(
        H2B, WoB, b_out, nullptr, nullptr, nullptr, nullptr, 0, logits);
}

// Round 4
// 224.701 us; speedup vs baseline: 1.1631x; 1.1631x over previous
//
#include <hip/hip_runtime.h>
#include <cstdint>
#include <cstddef>

typedef __bf16 bf16x8 __attribute__((ext_vector_type(8)));
typedef float  f32x4  __attribute__((ext_vector_type(4)));

static __device__ __forceinline__ unsigned short f2bf(float f) {
    union { float f; unsigned int u; } v;
    v.f = f;
    unsigned int r = v.u + 0x7FFFu + ((v.u >> 16) & 1u);
    return (unsigned short)(r >> 16);
}

static __device__ __forceinline__ float sigm(float x) {
    return 1.0f / (1.0f + __expf(-x));
}
static __device__ __forceinline__ float tanh_f(float x) {
    float e = __expf(2.0f * x);
    return 1.0f - 2.0f / (e + 1.0f);
}

#define GLD16(srcp, dstp) __builtin_amdgcn_global_load_lds( \
    (__attribute__((address_space(1))) void*)(srcp),        \
    (__attribute__((address_space(3))) void*)(dstp), 16, 0, 0)

// ---------------- prep kernels ----------------

__global__ void embed_cat(const int* __restrict__ bv, const int* __restrict__ i0,
                          const int* __restrict__ i1, const int* __restrict__ i2,
                          const int* __restrict__ i3, const float* __restrict__ num,
                          const float* __restrict__ bt, const float* __restrict__ t0,
                          const float* __restrict__ t1, const float* __restrict__ t2,
                          const float* __restrict__ t3, unsigned short* __restrict__ XB0)
{
    int col = blockIdx.x * 256 + threadIdx.x;
    int row = blockIdx.y;
    if (col >= 1472) return;
    int t = col / 92;
    int c = col - t * 92;
    int p = row * 16 + t;
    float v;
    if (c < 32)      v = bt[bv[p] * 32 + c];
    else if (c < 45) v = t0[i0[p] * 13 + (c - 32)];
    else if (c < 51) v = t1[i1[p] * 6  + (c - 45)];
    else if (c < 55) v = t2[i2[p] * 4  + (c - 51)];
    else if (c < 84) v = t3[i3[p] * 29 + (c - 55)];
    else             v = num[p * 8 + (c - 84)];
    XB0[(size_t)row * 1984 + col] = f2bf(v);
}

__global__ void h0_cast(const float* __restrict__ h0, unsigned short* __restrict__ XB0,
                        unsigned short* __restrict__ XB1)
{
    int col = blockIdx.x * 256 + threadIdx.x;   // 0..511
    int row = blockIdx.y;
    XB0[(size_t)row * 1984 + 1472 + col] = f2bf(h0[(size_t)row * 512 + col]);
    XB1[(size_t)row * 1024 + 512  + col] = f2bf(h0[(size_t)4194304 + (size_t)row * 512 + col]);
}

__global__ void pack_w(const float* __restrict__ Wih, const float* __restrict__ Whh,
                       unsigned short* __restrict__ WB, int Kih, int Ktot)
{
    int col = blockIdx.x * 256 + threadIdx.x;
    int np  = blockIdx.y;
    if (col >= Ktot) return;
    int jj = np >> 2, g = np & 3;
    int src = g * 512 + jj;
    float v = (col < Kih) ? Wih[(size_t)src * Kih + col]
                          : Whh[(size_t)src * 512 + (col - Kih)];
    WB[(size_t)np * Ktot + col] = f2bf(v);
}

__global__ void cast_w(const float* __restrict__ W, unsigned short* __restrict__ WB, int n) {
    int i = blockIdx.x * 256 + threadIdx.x;
    if (i < n) WB[i] = f2bf(W[i]);
}

__global__ void pack_bias(const float* __restrict__ bi0, const float* __restrict__ bh0,
                          const float* __restrict__ bi1, const float* __restrict__ bh1,
                          float* __restrict__ B0, float* __restrict__ B1)
{
    int np = blockIdx.x * 256 + threadIdx.x;   // 0..2047
    int jj = np >> 2, g = np & 3;
    int src = g * 512 + jj;
    B0[np] = bi0[src] + bh0[src];
    B1[np] = bi1[src] + bh1[src];
}

// ---------------- fused GEMM (+optional LSTM epilogue) ----------------
// C[m][n'] = sum_k A[m][k] * Bw[n'][k]   (A: [M][K] bf16, Bw: [N][K] bf16, both row-major)
// Tile 128x128, BK=64, 4 waves (2x2), each wave 64x64 via 4x4 mfma_f32_16x16x32_bf16 frags.
// Round-3 post-mortem: at LDS=51200B the HW gave only 2 blocks/CU (22.5% occ) regardless
// of launch_bounds. Epilogue scratch `gt` now ALIASES As/Bs (dead during epilogue):
// LDS 51200 -> 32768 B -> 4+ blocks/CU.
template<int K, bool LSTM, int NOUT>
__global__ __launch_bounds__(256, 4)
void gemm_fused(const unsigned short* __restrict__ A,
                const unsigned short* __restrict__ Bw,
                const float* __restrict__ bias,      // LSTM: interleaved b_ih+b_hh [2048]; else b_out
                const float* __restrict__ c_in,      // LSTM: [M][512]
                float* __restrict__ h_out,           // LSTM: [M][512]
                float* __restrict__ c_out,           // LSTM: [M][512]
                unsigned short* __restrict__ h_bf,   // LSTM: bf16 h for next GEMM
                int hb_stride,
                float* __restrict__ out_plain)       // !LSTM: [M][NOUT]
{
    // single allocation: [As | Bs] during K-loop; reused as gate-scratch in epilogue
    __shared__ __align__(16) unsigned short AsBs[2 * 128 * 64];
    unsigned short* As = AsBs;
    unsigned short* Bs = AsBs + 128 * 64;

    const int tid  = threadIdx.x;
    const int lane = tid & 63;
    const int wid  = tid >> 6;
    const int wm   = wid >> 1;
    const int wn   = wid & 1;
    const int rowBase = blockIdx.y * 128;
    const int colBase = blockIdx.x * 128;

    const int lr = lane >> 3;          // row within 8-row chunk
    const int lc = (lane & 7) * 8;     // col (elements) within 64

    f32x4 acc[4][4] = {};

    const unsigned short* aSrc0 = A  + (size_t)(rowBase + wid * 32 + lr) * K + lc;
    const unsigned short* bSrc0 = Bw + (size_t)(colBase + wid * 32 + lr) * K + lc;

    #pragma unroll 1
    for (int k0 = 0; k0 < K; k0 += 64) {
        #pragma unroll
        for (int t = 0; t < 4; ++t)
            GLD16(aSrc0 + (size_t)t * 8 * K + k0, &As[(wid * 4 + t) * 512]);
        #pragma unroll
        for (int t = 0; t < 4; ++t)
            GLD16(bSrc0 + (size_t)t * 8 * K + k0, &Bs[(wid * 4 + t) * 512]);
        __syncthreads();
        #pragma unroll
        for (int ks = 0; ks < 2; ++ks) {
            bf16x8 af[4], bfr[4];
            #pragma unroll
            for (int i = 0; i < 4; ++i)
                af[i] = *(const bf16x8*)&As[(wm * 64 + i * 16 + (lane & 15)) * 64 + ks * 32 + (lane >> 4) * 8];
            #pragma unroll
            for (int i = 0; i < 4; ++i)
                bfr[i] = *(const bf16x8*)&Bs[(wn * 64 + i * 16 + (lane & 15)) * 64 + ks * 32 + (lane >> 4) * 8];
            #pragma unroll
            for (int i = 0; i < 4; ++i) {
                #pragma unroll
                for (int j = 0; j < 4; ++j)
                    acc[i][j] = __builtin_amdgcn_mfma_f32_16x16x32_bf16(af[i], bfr[j], acc[i][j], 0, 0, 0);
            }
        }
        __syncthreads();
    }

    if constexpr (!LSTM) {
        // plain epilogue: out = acc + bias (C layout: col=lane&15, row=(lane>>4)*4+r, m89-verified)
        #pragma unroll
        for (int i = 0; i < 4; ++i) {
            int grow = rowBase + wm * 64 + i * 16 + (lane >> 4) * 4;
            #pragma unroll
            for (int j = 0; j < 4; ++j) {
                int gcol = colBase + wn * 64 + j * 16 + (lane & 15);
                float b = bias[gcol];
                #pragma unroll
                for (int r = 0; r < 4; ++r)
                    out_plain[(size_t)(grow + r) * NOUT + gcol] = acc[i][j][r] + b;
            }
        }
    } else {
        // LSTM epilogue: cols are interleaved gates n' = 4*j + {i,f,g,o}
        // NOTE: i-loop MUST be fully unrolled — a rolled loop makes acc[i][..]
        // runtime-indexed and demotes the whole accumulator to scratch
        // (rule #20; round-1 post-mortem: 3 GB scratch writebacks, MfmaUtil 0.6%).
        // gt scratch aliases AsBs (dead after final K-loop barrier).
        float* gtw = reinterpret_cast<float*>(AsBs) + wid * (16 * 72);
        const int jBase = (colBase + wn * 64) >> 2;   // global hidden-unit base (16 per wave tile)
        #pragma unroll
        for (int i = 0; i < 4; ++i) {
            #pragma unroll
            for (int j = 0; j < 4; ++j) {
                int cl = j * 16 + (lane & 15);
                int rl = (lane >> 4) * 4;
                #pragma unroll
                for (int r = 0; r < 4; ++r)
                    gtw[(rl + r) * 72 + cl] = acc[i][j][r];
            }
            __syncthreads();
            #pragma unroll
            for (int q = 0; q < 4; ++q) {
                int p  = lane + q * 64;            // 256 outputs: 16 rows x 16 hidden units
                int rl = p >> 4;
                int jl = p & 15;
                float4 g4 = *(const float4*)&gtw[rl * 72 + jl * 4];
                float4 b4 = *(const float4*)&bias[(jBase + jl) * 4];
                float xi = g4.x + b4.x;
                float xf = g4.y + b4.y;
                float xg = g4.z + b4.z;
                float xo = g4.w + b4.w;
                float iv = sigm(xi), fv = sigm(xf), gv = tanh_f(xg), ov = sigm(xo);
                int grow = rowBase + wm * 64 + i * 16 + rl;
                int gj   = jBase + jl;
                size_t idx = (size_t)grow * 512 + gj;
                float cp = c_in[idx];
                float cn = fv * cp + iv * gv;
                float hn = ov * tanh_f(cn);
                h_out[idx] = hn;
                c_out[idx] = cn;
                h_bf[(size_t)grow * hb_stride + gj] = f2bf(hn);
            }
            __syncthreads();
        }
    }
}

// ---------------- launch ----------------

extern "C" void kernel_launch(void* const* d_in, const int* in_sizes, int n_in,
                              void* d_out, int out_size, void* d_ws, size_t ws_size,
                              hipStream_t stream) {
    (void)in_sizes; (void)n_in; (void)out_size; (void)ws_size;

    const int*   byte_vals = (const int*)d_in[0];
    const int*   ci0       = (const int*)d_in[1];
    const int*   ci1       = (const int*)d_in[2];
    const int*   ci2       = (const int*)d_in[3];
    const int*   ci3       = (const int*)d_in[4];
    const float* numer     = (const float*)d_in[5];
    const float* h0        = (const float*)d_in[6];
    const float* c0        = (const float*)d_in[7];
    const float* byte_tab  = (const float*)d_in[8];
    const float* cat_t0    = (const float*)d_in[9];
    const float* cat_t1    = (const float*)d_in[10];
    const float* cat_t2    = (const float*)d_in[11];
    const float* cat_t3    = (const float*)d_in[12];
    const float* W_ih0     = (const float*)d_in[13];
    const float* W_hh0     = (const float*)d_in[14];
    const float* b_ih0     = (const float*)d_in[15];
    const float* b_hh0     = (const float*)d_in[16];
    const float* W_ih1     = (const float*)d_in[17];
    const float* W_hh1     = (const float*)d_in[18];
    const float* b_ih1     = (const float*)d_in[19];
    const float* b_hh1     = (const float*)d_in[20];
    const float* W_out     = (const float*)d_in[21];
    const float* b_out     = (const float*)d_in[22];

    char* ws = (char*)d_ws;
    unsigned short* XB0 = (unsigned short*)(ws);               // 8192*1984*2 = 32,505,856
    unsigned short* XB1 = (unsigned short*)(ws + 32505856);    // 8192*1024*2 = 16,777,216
    unsigned short* WB0 = (unsigned short*)(ws + 49283072);    // 2048*1984*2 =  8,126,464
    unsigned short* WB1 = (unsigned short*)(ws + 57409536);    // 2048*1024*2 =  4,194,304
    unsigned short* WoB = (unsigned short*)(ws + 61603840);    // 256*512*2   =    262,144
    float*          B0  = (float*)(ws + 61865984);             // 2048*4
    float*          B1  = (float*)(ws + 61874176);             // 2048*4  (end 61,882,368)
    unsigned short* H2B = XB0;                                 // alias: XB0 dead after GEMM0

    float* out    = (float*)d_out;
    float* logits = out;                        // [8192][256]
    float* h1o    = out + 2097152;              // h stack [0]
    float* h2o    = out + 2097152 + 4194304;    // h stack [1]
    float* c1o    = out + 2097152 + 8388608;    // c stack [0]
    float* c2o    = out + 2097152 + 12582912;   // c stack [1]
    const float* c0_0 = c0;
    const float* c0_1 = c0 + 4194304;

    // prep
    embed_cat<<<dim3(6, 8192), 256, 0, stream>>>(byte_vals, ci0, ci1, ci2, ci3, numer,
                                                 byte_tab, cat_t0, cat_t1, cat_t2, cat_t3, XB0);
    h0_cast<<<dim3(2, 8192), 256, 0, stream>>>(h0, XB0, XB1);
    pack_w<<<dim3(8, 2048), 256, 0, stream>>>(W_ih0, W_hh0, WB0, 1472, 1984);
    pack_w<<<dim3(4, 2048), 256, 0, stream>>>(W_ih1, W_hh1, WB1, 512, 1024);
    cast_w<<<dim3(512), 256, 0, stream>>>(W_out, WoB, 131072);
    pack_bias<<<dim3(8), 256, 0, stream>>>(b_ih0, b_hh0, b_ih1, b_hh1, B0, B1);

    // layer 0: gates0 = [x | h0_0] @ [W_ih0 | W_hh0]^T (interleaved), fused LSTM -> h1,c1, h1_bf16 -> XB1[:, :512]
    gemm_fused<1984, true, 512><<<dim3(16, 64), 256, 0, stream>>>(
        XB0, WB0, B0, c0_0, h1o, c1o, XB1, 1024, nullptr);

    // layer 1: gates1 = [h1 | h0_1] @ [W_ih1 | W_hh1]^T, fused LSTM -> h2,c2, h2_bf16 -> H2B
    gemm_fused<1024, true, 512><<<dim3(16, 64), 256, 0, stream>>>(
        XB1, WB1, B1, c0_1, h2o, c2o, H2B, 512, nullptr);

    // logits = h2 @ W_out^T + b_out
    gemm_fused<512, false, 256><<<dim3(2, 64), 256, 0, stream>>>(
        H2B, WoB, b_out, nullptr, nullptr, nullptr, nullptr, 0, logits);
}

// Round 5
// 215.734 us; speedup vs baseline: 1.2114x; 1.0416x over previous
//
#include <hip/hip_runtime.h>
#include <cstdint>
#include <cstddef>

typedef __bf16 bf16x8 __attribute__((ext_vector_type(8)));
typedef float  f32x4  __attribute__((ext_vector_type(4)));

static __device__ __forceinline__ unsigned short f2bf(float f) {
    union { float f; unsigned int u; } v;
    v.f = f;
    unsigned int r = v.u + 0x7FFFu + ((v.u >> 16) & 1u);
    return (unsigned short)(r >> 16);
}

static __device__ __forceinline__ float sigm(float x) {
    return 1.0f / (1.0f + __expf(-x));
}
static __device__ __forceinline__ float tanh_f(float x) {
    float e = __expf(2.0f * x);
    return 1.0f - 2.0f / (e + 1.0f);
}

#define GLD16(srcp, dstp) __builtin_amdgcn_global_load_lds( \
    (__attribute__((address_space(1))) void*)(srcp),        \
    (__attribute__((address_space(3))) void*)(dstp), 16, 0, 0)

#define LGKM0() do { asm volatile("s_waitcnt lgkmcnt(0)" ::: "memory"); \
                     __builtin_amdgcn_sched_barrier(0); } while(0)

// ---------------- prep kernels ----------------

__global__ void embed_cat(const int* __restrict__ bv, const int* __restrict__ i0,
                          const int* __restrict__ i1, const int* __restrict__ i2,
                          const int* __restrict__ i3, const float* __restrict__ num,
                          const float* __restrict__ bt, const float* __restrict__ t0,
                          const float* __restrict__ t1, const float* __restrict__ t2,
                          const float* __restrict__ t3, unsigned short* __restrict__ XB0)
{
    int col = blockIdx.x * 256 + threadIdx.x;
    int row = blockIdx.y;
    if (col >= 1472) return;
    int t = col / 92;
    int c = col - t * 92;
    int p = row * 16 + t;
    float v;
    if (c < 32)      v = bt[bv[p] * 32 + c];
    else if (c < 45) v = t0[i0[p] * 13 + (c - 32)];
    else if (c < 51) v = t1[i1[p] * 6  + (c - 45)];
    else if (c < 55) v = t2[i2[p] * 4  + (c - 51)];
    else if (c < 84) v = t3[i3[p] * 29 + (c - 55)];
    else             v = num[p * 8 + (c - 84)];
    XB0[(size_t)row * 1984 + col] = f2bf(v);
}

__global__ void h0_cast(const float* __restrict__ h0, unsigned short* __restrict__ XB0,
                        unsigned short* __restrict__ XB1)
{
    int col = blockIdx.x * 256 + threadIdx.x;   // 0..511
    int row = blockIdx.y;
    XB0[(size_t)row * 1984 + 1472 + col] = f2bf(h0[(size_t)row * 512 + col]);
    XB1[(size_t)row * 1024 + 512  + col] = f2bf(h0[(size_t)4194304 + (size_t)row * 512 + col]);
}

__global__ void pack_w(const float* __restrict__ Wih, const float* __restrict__ Whh,
                       unsigned short* __restrict__ WB, int Kih, int Ktot)
{
    int col = blockIdx.x * 256 + threadIdx.x;
    int np  = blockIdx.y;
    if (col >= Ktot) return;
    int jj = np >> 2, g = np & 3;
    int src = g * 512 + jj;
    float v = (col < Kih) ? Wih[(size_t)src * Kih + col]
                          : Whh[(size_t)src * 512 + (col - Kih)];
    WB[(size_t)np * Ktot + col] = f2bf(v);
}

__global__ void cast_w(const float* __restrict__ W, unsigned short* __restrict__ WB, int n) {
    int i = blockIdx.x * 256 + threadIdx.x;
    if (i < n) WB[i] = f2bf(W[i]);
}

__global__ void pack_bias(const float* __restrict__ bi0, const float* __restrict__ bh0,
                          const float* __restrict__ bi1, const float* __restrict__ bh1,
                          float* __restrict__ B0, float* __restrict__ B1)
{
    int np = blockIdx.x * 256 + threadIdx.x;   // 0..2047
    int jj = np >> 2, g = np & 3;
    int src = g * 512 + jj;
    B0[np] = bi0[src] + bh0[src];
    B1[np] = bi1[src] + bh1[src];
}

// ---------------- 256x256 8-phase GEMM + fused LSTM epilogue ----------------
// C[m][n'] = sum_k A[m][k] * Bw[n'][k]; gates interleaved n' = 4*j + {i,f,g,o}.
// 512 threads = 8 waves (2M x 4N); per-wave 128x64 out = acc[8][4] f32x4.
// LDS (dynamic, 128 KiB): A: 2 slots x 2 halves x (128x64 bf16 = 16KB); B same.
// Per K-tile: 4 phases {ds_reads | stage 1 half | bar | lgkm0 | prio1 | 16 MFMA | prio0 | bar}.
// Staging stream during tile t: t+1:B1 (p0), t+2:A0 (p1), t+2:A1 (p2), t+2:B0 (p3).
// Safety: A-h0 readers (wm0) read ALL A in p0; wm1 reads split p0/p1; B nh0 in p0, nh1 in p2;
// per-phase lgkmcnt(0) drains every issued ds_read before its half can be overwritten.
// vmcnt(6) at p3 (3 half-tiles in flight, T4); vmcnt(0) at t==nt-2 to drain.
// LDS swizzle (T2): 16B-slot ^= (row&7), pre-applied on the GLOBAL source (rule #21),
// re-applied on ds_read address (row&7 == lane&7 for all frag reads).
template<int K>
__global__ __launch_bounds__(512, 2)
void gemm256_lstm(const unsigned short* __restrict__ Aa,
                  const unsigned short* __restrict__ Bw,
                  const float* __restrict__ bias,
                  const float* __restrict__ c_in,
                  float* __restrict__ h_out,
                  float* __restrict__ c_out,
                  unsigned short* __restrict__ h_bf,
                  int hb_stride)
{
    extern __shared__ unsigned short lds[];   // 65536 shorts = 128 KiB
    constexpr int nt = K / 64;

    const int tid  = threadIdx.x;
    const int lane = tid & 63;
    const int wid  = tid >> 6;       // 0..7
    const int wm   = wid >> 2;       // 0..1
    const int wn   = wid & 3;        // 0..3
    const int bx   = blockIdx.x;     // 8
    const int by   = blockIdx.y;     // 32
    const int ln15 = lane & 15;
    const int l16  = lane >> 4;
    const int swz7 = lane & 7;
    const int cSwz = ((tid & 7) ^ ((tid >> 3) & 7)) * 8;   // pre-swizzled src col (elements)

    f32x4 acc[8][4] = {};
    bf16x8 af[8][2];
    bf16x8 bfr[4][2];

    auto STAGE = [&](int op, int t, int h) {
        const unsigned short* src = op ? Bw : Aa;
        const int pbase = (op ? bx : by) * 256 + h * 128 + (tid >> 3);
        const unsigned short* s0 = src + (size_t)pbase * K + t * 64 + cSwz;
        unsigned short* d = lds + op * 32768 + ((t & 1) * 2 + h) * 8192 + tid * 8;
        GLD16(s0, d);
        GLD16(s0 + (size_t)64 * K, d + 4096);
    };
    auto LD_A = [&](int t, int f, int ks) -> bf16x8 {
        return *(const bf16x8*)&lds[(t & 1) * 16384 + wm * 8192 +
                                    (f * 16 + ln15) * 64 + ((ks * 4 + l16) ^ swz7) * 8];
    };
    auto LD_B = [&](int t, int nf, int ks) -> bf16x8 {
        return *(const bf16x8*)&lds[32768 + (t & 1) * 16384 + (wn >> 1) * 8192 +
                                    ((wn & 1) * 64 + nf * 16 + ln15) * 64 + ((ks * 4 + l16) ^ swz7) * 8];
    };

#define QUAD(MH, NH) do {                                                         \
    _Pragma("unroll") for (int m_ = 0; m_ < 4; ++m_)                              \
    _Pragma("unroll") for (int n_ = 0; n_ < 2; ++n_) {                            \
        acc[(MH)*4+m_][(NH)*2+n_] = __builtin_amdgcn_mfma_f32_16x16x32_bf16(      \
            af[(MH)*4+m_][0], bfr[(NH)*2+n_][0], acc[(MH)*4+m_][(NH)*2+n_],0,0,0);\
        acc[(MH)*4+m_][(NH)*2+n_] = __builtin_amdgcn_mfma_f32_16x16x32_bf16(      \
            af[(MH)*4+m_][1], bfr[(NH)*2+n_][1], acc[(MH)*4+m_][(NH)*2+n_],0,0,0);\
    } } while (0)

    // prologue: tile0 all 4 halves + tile1 {A0, A1, B0}  (7 halves = 14 loads/wave)
    STAGE(0, 0, 0); STAGE(0, 0, 1); STAGE(1, 0, 0); STAGE(1, 0, 1);
    STAGE(0, 1, 0); STAGE(0, 1, 1); STAGE(1, 1, 0);
    asm volatile("s_waitcnt vmcnt(6)" ::: "memory");
    __builtin_amdgcn_s_barrier();

    #pragma unroll 1
    for (int t = 0; t < nt; ++t) {
        // ---- phase 0: quadrant (0,0) ----
        if (wm == 0) {
            #pragma unroll
            for (int f = 0; f < 8; ++f) { af[f][0] = LD_A(t, f, 0); af[f][1] = LD_A(t, f, 1); }
        } else {
            #pragma unroll
            for (int f = 0; f < 4; ++f) { af[f][0] = LD_A(t, f, 0); af[f][1] = LD_A(t, f, 1); }
        }
        #pragma unroll
        for (int n = 0; n < 2; ++n) { bfr[n][0] = LD_B(t, n, 0); bfr[n][1] = LD_B(t, n, 1); }
        if (t + 1 < nt) STAGE(1, t + 1, 1);
        __builtin_amdgcn_s_barrier();
        LGKM0();
        __builtin_amdgcn_s_setprio(1);
        QUAD(0, 0);
        __builtin_amdgcn_s_setprio(0);
        __builtin_amdgcn_s_barrier();

        // ---- phase 1: quadrant (1,0) ----
        if (wm == 1) {
            #pragma unroll
            for (int f = 4; f < 8; ++f) { af[f][0] = LD_A(t, f, 0); af[f][1] = LD_A(t, f, 1); }
        }
        if (t + 2 < nt) STAGE(0, t + 2, 0);
        __builtin_amdgcn_s_barrier();
        LGKM0();
        __builtin_amdgcn_s_setprio(1);
        QUAD(1, 0);
        __builtin_amdgcn_s_setprio(0);
        __builtin_amdgcn_s_barrier();

        // ---- phase 2: quadrant (1,1) ----
        #pragma unroll
        for (int n = 2; n < 4; ++n) { bfr[n][0] = LD_B(t, n, 0); bfr[n][1] = LD_B(t, n, 1); }
        if (t + 2 < nt) STAGE(0, t + 2, 1);
        __builtin_amdgcn_s_barrier();
        LGKM0();
        __builtin_amdgcn_s_setprio(1);
        QUAD(1, 1);
        __builtin_amdgcn_s_setprio(0);
        __builtin_amdgcn_s_barrier();

        // ---- phase 3: quadrant (0,1) ----
        if (t + 2 < nt) STAGE(1, t + 2, 0);
        __builtin_amdgcn_s_barrier();
        LGKM0();
        __builtin_amdgcn_s_setprio(1);
        QUAD(0, 1);
        __builtin_amdgcn_s_setprio(0);
        if (t + 2 < nt) {
            asm volatile("s_waitcnt vmcnt(6)" ::: "memory");
        } else if (t + 1 < nt) {
            asm volatile("s_waitcnt vmcnt(0)" ::: "memory");
        }
        __builtin_amdgcn_s_barrier();
    }
#undef QUAD

    // ---- fused LSTM epilogue (wave-local LDS slab, aliases staging LDS) ----
    float* gtw = reinterpret_cast<float*>(lds) + wid * (16 * 72);
    const int jBase = (bx * 256 + wn * 64) >> 2;
    #pragma unroll
    for (int f = 0; f < 8; ++f) {
        #pragma unroll
        for (int n = 0; n < 4; ++n) {
            int cl = n * 16 + ln15;
            int rl = l16 * 4;
            #pragma unroll
            for (int r = 0; r < 4; ++r)
                gtw[(rl + r) * 72 + cl] = acc[f][n][r];
        }
        #pragma unroll
        for (int q = 0; q < 4; ++q) {
            int p  = lane + q * 64;
            int rl = p >> 4;
            int jl = p & 15;
            float4 g4 = *(const float4*)&gtw[rl * 72 + jl * 4];
            float4 b4 = *(const float4*)&bias[(jBase + jl) * 4];
            float xi = g4.x + b4.x;
            float xf = g4.y + b4.y;
            float xg = g4.z + b4.z;
            float xo = g4.w + b4.w;
            float iv = sigm(xi), fv = sigm(xf), gv = tanh_f(xg), ov = sigm(xo);
            int grow = by * 256 + wm * 128 + f * 16 + rl;
            int gj   = jBase + jl;
            size_t idx = (size_t)grow * 512 + gj;
            float cp = c_in[idx];
            float cn = fv * cp + iv * gv;
            float hn = ov * tanh_f(cn);
            h_out[idx] = hn;
            c_out[idx] = cn;
            h_bf[(size_t)grow * hb_stride + gj] = f2bf(hn);
        }
    }
}

// ---------------- 128x128 plain GEMM (logits) ----------------
template<int K, int NOUT>
__global__ __launch_bounds__(256, 4)
void gemm_plain(const unsigned short* __restrict__ A,
                const unsigned short* __restrict__ Bw,
                const float* __restrict__ bias,
                float* __restrict__ out_plain)
{
    __shared__ __align__(16) unsigned short AsBs[2 * 128 * 64];
    unsigned short* As = AsBs;
    unsigned short* Bs = AsBs + 128 * 64;

    const int tid  = threadIdx.x;
    const int lane = tid & 63;
    const int wid  = tid >> 6;
    const int wm   = wid >> 1;
    const int wn   = wid & 1;
    const int rowBase = blockIdx.y * 128;
    const int colBase = blockIdx.x * 128;

    const int lr = lane >> 3;
    const int lc = (lane & 7) * 8;

    f32x4 acc[4][4] = {};

    const unsigned short* aSrc0 = A  + (size_t)(rowBase + wid * 32 + lr) * K + lc;
    const unsigned short* bSrc0 = Bw + (size_t)(colBase + wid * 32 + lr) * K + lc;

    #pragma unroll 1
    for (int k0 = 0; k0 < K; k0 += 64) {
        #pragma unroll
        for (int t = 0; t < 4; ++t)
            GLD16(aSrc0 + (size_t)t * 8 * K + k0, &As[(wid * 4 + t) * 512]);
        #pragma unroll
        for (int t = 0; t < 4; ++t)
            GLD16(bSrc0 + (size_t)t * 8 * K + k0, &Bs[(wid * 4 + t) * 512]);
        __syncthreads();
        #pragma unroll
        for (int ks = 0; ks < 2; ++ks) {
            bf16x8 af[4], bfr[4];
            #pragma unroll
            for (int i = 0; i < 4; ++i)
                af[i] = *(const bf16x8*)&As[(wm * 64 + i * 16 + (lane & 15)) * 64 + ks * 32 + (lane >> 4) * 8];
            #pragma unroll
            for (int i = 0; i < 4; ++i)
                bfr[i] = *(const bf16x8*)&Bs[(wn * 64 + i * 16 + (lane & 15)) * 64 + ks * 32 + (lane >> 4) * 8];
            #pragma unroll
            for (int i = 0; i < 4; ++i) {
                #pragma unroll
                for (int j = 0; j < 4; ++j)
                    acc[i][j] = __builtin_amdgcn_mfma_f32_16x16x32_bf16(af[i], bfr[j], acc[i][j], 0, 0, 0);
            }
        }
        __syncthreads();
    }

    #pragma unroll
    for (int i = 0; i < 4; ++i) {
        int grow = rowBase + wm * 64 + i * 16 + (lane >> 4) * 4;
        #pragma unroll
        for (int j = 0; j < 4; ++j) {
            int gcol = colBase + wn * 64 + j * 16 + (lane & 15);
            float b = bias[gcol];
            #pragma unroll
            for (int r = 0; r < 4; ++r)
                out_plain[(size_t)(grow + r) * NOUT + gcol] = acc[i][j][r] + b;
        }
    }
}

// ---------------- launch ----------------

extern "C" void kernel_launch(void* const* d_in, const int* in_sizes, int n_in,
                              void* d_out, int out_size, void* d_ws, size_t ws_size,
                              hipStream_t stream) {
    (void)in_sizes; (void)n_in; (void)out_size; (void)ws_size;

    const int*   byte_vals = (const int*)d_in[0];
    const int*   ci0       = (const int*)d_in[1];
    const int*   ci1       = (const int*)d_in[2];
    const int*   ci2       = (const int*)d_in[3];
    const int*   ci3       = (const int*)d_in[4];
    const float* numer     = (const float*)d_in[5];
    const float* h0        = (const float*)d_in[6];
    const float* c0        = (const float*)d_in[7];
    const float* byte_tab  = (const float*)d_in[8];
    const float* cat_t0    = (const float*)d_in[9];
    const float* cat_t1    = (const float*)d_in[10];
    const float* cat_t2    = (const float*)d_in[11];
    const float* cat_t3    = (const float*)d_in[12];
    const float* W_ih0     = (const float*)d_in[13];
    const float* W_hh0     = (const float*)d_in[14];
    const float* b_ih0     = (const float*)d_in[15];
    const float* b_hh0     = (const float*)d_in[16];
    const float* W_ih1     = (const float*)d_in[17];
    const float* W_hh1     = (const float*)d_in[18];
    const float* b_ih1     = (const float*)d_in[19];
    const float* b_hh1     = (const float*)d_in[20];
    const float* W_out     = (const float*)d_in[21];
    const float* b_out     = (const float*)d_in[22];

    char* ws = (char*)d_ws;
    unsigned short* XB0 = (unsigned short*)(ws);               // 8192*1984*2 = 32,505,856
    unsigned short* XB1 = (unsigned short*)(ws + 32505856);    // 8192*1024*2 = 16,777,216
    unsigned short* WB0 = (unsigned short*)(ws + 49283072);    // 2048*1984*2 =  8,126,464
    unsigned short* WB1 = (unsigned short*)(ws + 57409536);    // 2048*1024*2 =  4,194,304
    unsigned short* WoB = (unsigned short*)(ws + 61603840);    // 256*512*2   =    262,144
    float*          B0  = (float*)(ws + 61865984);             // 2048*4
    float*          B1  = (float*)(ws + 61874176);             // 2048*4  (end 61,882,368)
    unsigned short* H2B = XB0;                                 // alias: XB0 dead after GEMM0

    float* out    = (float*)d_out;
    float* logits = out;                        // [8192][256]
    float* h1o    = out + 2097152;              // h stack [0]
    float* h2o    = out + 2097152 + 4194304;    // h stack [1]
    float* c1o    = out + 2097152 + 8388608;    // c stack [0]
    float* c2o    = out + 2097152 + 12582912;   // c stack [1]
    const float* c0_0 = c0;
    const float* c0_1 = c0 + 4194304;

    // prep
    embed_cat<<<dim3(6, 8192), 256, 0, stream>>>(byte_vals, ci0, ci1, ci2, ci3, numer,
                                                 byte_tab, cat_t0, cat_t1, cat_t2, cat_t3, XB0);
    h0_cast<<<dim3(2, 8192), 256, 0, stream>>>(h0, XB0, XB1);
    pack_w<<<dim3(8, 2048), 256, 0, stream>>>(W_ih0, W_hh0, WB0, 1472, 1984);
    pack_w<<<dim3(4, 2048), 256, 0, stream>>>(W_ih1, W_hh1, WB1, 512, 1024);
    cast_w<<<dim3(512), 256, 0, stream>>>(W_out, WoB, 131072);
    pack_bias<<<dim3(8), 256, 0, stream>>>(b_ih0, b_hh0, b_ih1, b_hh1, B0, B1);

    // layer 0: gates0 = [x | h0_0] @ [W_ih0 | W_hh0]^T, fused LSTM -> h1,c1, h1_bf16 -> XB1[:, :512]
    gemm256_lstm<1984><<<dim3(8, 32), 512, 131072, stream>>>(
        XB0, WB0, B0, c0_0, h1o, c1o, XB1, 1024);

    // layer 1: gates1 = [h1 | h0_1] @ [W_ih1 | W_hh1]^T, fused LSTM -> h2,c2, h2_bf16 -> H2B
    gemm256_lstm<1024><<<dim3(8, 32), 512, 131072, stream>>>(
        XB1, WB1, B1, c0_1, h2o, c2o, H2B, 512);

    // logits = h2 @ W_out^T + b_out
    gemm_plain<512, 256><<<dim3(2, 64), 256, 0, stream>>>(H2B, WoB, b_out, logits);
}